// Round 1
// baseline (219.991 us; speedup 1.0000x reference)
//
#include <hip/hip_runtime.h>
#include <hip/hip_bf16.h>

// Problem constants
#define NROWS 262144
#define HISTC 24
#define FOREC 20

// MFMA fragment vector types (gfx950 16x16x32 bf16: v8bf16 in, v4f32 acc)
typedef __bf16        v8bf __attribute__((ext_vector_type(8)));
typedef float         v4f  __attribute__((ext_vector_type(4)));
typedef unsigned int  v4u  __attribute__((ext_vector_type(4)));
typedef unsigned int  v2u  __attribute__((ext_vector_type(2)));

// Workspace layout (bytes): [0..16) scalars a,b,g,lam ; then swizzled bf16 weights.
// Swizzle: block (ntile,ktile) of 64 lanes x 8 bf16, elem ((nt*KT+kt)*64 + lane)*8 + j
// holding W^T[feat = nt*16 + (lane&15)][k = kt*32 + (lane>>4)*8 + j]  (OOB -> 0).
#define WS_WT1_OFF 64
#define WT1_ELEMS 16384   /* 16 nt * 2 kt * 512 */
#define WT2_ELEMS 65536   /* 16 nt * 8 kt * 512 */
#define WT3_ELEMS 65536
#define WT4_ELEMS 8192    /*  2 nt * 8 kt * 512 */

__device__ __forceinline__ unsigned short f2bf(float x) {
    unsigned u = __builtin_bit_cast(unsigned, x);
    u += 0x7FFFu + ((u >> 16) & 1u);          // round-to-nearest-even
    return (unsigned short)(u >> 16);
}

__device__ __forceinline__ unsigned pack2bf(float a, float b) {
    unsigned ua = __builtin_bit_cast(unsigned, a);
    unsigned ub = __builtin_bit_cast(unsigned, b);
    ua += 0x7FFFu + ((ua >> 16) & 1u);
    ub += 0x7FFFu + ((ub >> 16) & 1u);
    return (ua >> 16) | (ub & 0xFFFF0000u);
}

// tanh(x) = 1 - 2/(exp2(2*log2e*x)+1); v_exp_f32 + v_rcp_f32, ~1e-6 abs err
__device__ __forceinline__ float fast_tanh(float x) {
    float t = x * 2.885390081777927f;
    float p = __builtin_amdgcn_exp2f(t);
    float r = __builtin_amdgcn_rcpf(p + 1.0f);
    return __builtin_fmaf(-2.0f, r, 1.0f);
}

// ---------------- prep: scalars + weight transpose/convert/swizzle ----------------
__global__ void prep_kernel(const float* __restrict__ w1, const float* __restrict__ w2,
                            const float* __restrict__ w3, const float* __restrict__ w4,
                            const float* __restrict__ alpha, const float* __restrict__ beta,
                            const float* __restrict__ gamma, const float* __restrict__ lmix,
                            unsigned char* __restrict__ ws)
{
    if (blockIdx.x == 608) {                    // scalar block
        int t = threadIdx.x;
        float* wsf = (float*)ws;
        if (t == 0) wsf[0] = 1.0f / (1.0f + expf(-alpha[0]));
        else if (t == 1) wsf[1] = 1.0f / (1.0f + expf(-beta[0]));
        else if (t == 2) wsf[2] = fabsf(gamma[0]);
        else if (t == 3) wsf[3] = 1.0f / (1.0f + expf(-lmix[0]));
        return;
    }
    int idx = blockIdx.x * 256 + threadIdx.x;   // 608*256 = 155648 elems exactly
    const float* src;
    int KT, Kreal, Nreal, srcN, local;
    unsigned short* dst = (unsigned short*)(ws + WS_WT1_OFF);
    if (idx < WT1_ELEMS) {
        local = idx; src = w1; KT = 2; Kreal = 44; Nreal = 256; srcN = 256;
    } else if (idx < WT1_ELEMS + WT2_ELEMS) {
        local = idx - WT1_ELEMS; dst += WT1_ELEMS;
        src = w2; KT = 8; Kreal = 256; Nreal = 256; srcN = 256;
    } else if (idx < WT1_ELEMS + WT2_ELEMS + WT3_ELEMS) {
        local = idx - (WT1_ELEMS + WT2_ELEMS); dst += WT1_ELEMS + WT2_ELEMS;
        src = w3; KT = 8; Kreal = 256; Nreal = 256; srcN = 256;
    } else {
        local = idx - (WT1_ELEMS + WT2_ELEMS + WT3_ELEMS);
        dst += WT1_ELEMS + WT2_ELEMS + WT3_ELEMS;
        src = w4; KT = 8; Kreal = 256; Nreal = 20; srcN = 20;
    }
    int j   = local & 7;
    int L   = (local >> 3) & 63;
    int blk = local >> 9;
    int kt = blk % KT, nt = blk / KT;
    int cc = L & 15,  qq = L >> 4;
    int feat = nt * 16 + cc;
    int k    = kt * 32 + qq * 8 + j;
    float v = (k < Kreal && feat < Nreal) ? src[k * srcN + feat] : 0.0f;
    dst[local] = f2bf(v);
}

// ---------------- fused main kernel ----------------
// Transposed compute Y^T = W^T X^T: A-operand = registered weight frags,
// B-operand = activations streamed from LDS [sample][feature] (stride 264 = +8 pad).
// Wave w owns features [w*64, w*64+64) (4 ftiles), all 64 samples (4 stiles).
template<int KT, int SIN>
__device__ __forceinline__ void layer123(unsigned short* buf,
        const unsigned short* __restrict__ wsw, const float* __restrict__ bias,
        int w, int c, int q, int lane)
{
    const v4u* wp = (const v4u*)wsw;
    v4u a[4][KT];
#pragma unroll
    for (int ft = 0; ft < 4; ++ft)
#pragma unroll
        for (int kt = 0; kt < KT; ++kt)
            a[ft][kt] = wp[((w * 4 + ft) * KT + kt) * 64 + lane];

    v4f acc[4][4];
#pragma unroll
    for (int ft = 0; ft < 4; ++ft)
#pragma unroll
        for (int st = 0; st < 4; ++st) {
            v4f z = {0.0f, 0.0f, 0.0f, 0.0f};
            acc[ft][st] = z;
        }

#pragma unroll
    for (int st = 0; st < 4; ++st)
#pragma unroll
        for (int kt = 0; kt < KT; ++kt) {
            v4u braw = *(const v4u*)&buf[(st * 16 + c) * SIN + kt * 32 + q * 8];
            v8bf bb = __builtin_bit_cast(v8bf, braw);
#pragma unroll
            for (int ft = 0; ft < 4; ++ft)
                acc[ft][st] = __builtin_amdgcn_mfma_f32_16x16x32_bf16(
                    __builtin_bit_cast(v8bf, a[ft][kt]), bb, acc[ft][st], 0, 0, 0);
        }

    __syncthreads();   // all reads done before in-place overwrite

    // Epilogue: C gives lane (q,c) -> sample c (fixed), 4 consecutive features q*4+r
    // per tile -> pack bf16 pairs, ds_write_b64 into [sample][feature].
#pragma unroll
    for (int ft = 0; ft < 4; ++ft) {
        v4f bi = *(const v4f*)&bias[w * 64 + ft * 16 + q * 4];
#pragma unroll
        for (int st = 0; st < 4; ++st) {
            float x0 = fast_tanh(acc[ft][st][0] + bi[0]);
            float x1 = fast_tanh(acc[ft][st][1] + bi[1]);
            float x2 = fast_tanh(acc[ft][st][2] + bi[2]);
            float x3 = fast_tanh(acc[ft][st][3] + bi[3]);
            v2u d; d[0] = pack2bf(x0, x1); d[1] = pack2bf(x2, x3);
            *(v2u*)&buf[(st * 16 + c) * 264 + w * 64 + ft * 16 + q * 4] = d;
        }
    }
    __syncthreads();
}

__global__ __launch_bounds__(256, 2) void fused_kernel(
    const float* __restrict__ history,
    const float* __restrict__ eb1, const float* __restrict__ eb2,
    const float* __restrict__ cb1, const float* __restrict__ cb2,
    const unsigned char* __restrict__ ws, float* __restrict__ out)
{
    __shared__ unsigned short buf[64 * 264];   // 33792 B, in-place act buffer
    __shared__ float tp[64 * 20];              // 5120 B fp32 T_physics

    const int tid  = threadIdx.x;
    const int w    = tid >> 6;
    const int lane = tid & 63;
    const int c    = lane & 15;
    const int q    = lane >> 4;
    const int row0 = blockIdx.x << 6;          // 64 samples per WG
    const float* wsf = (const float*)ws;
    const unsigned short* wt1 = (const unsigned short*)(ws + WS_WT1_OFF);
    const unsigned short* wt2 = wt1 + WT1_ELEMS;
    const unsigned short* wt3 = wt2 + WT2_ELEMS;
    const unsigned short* wt4 = wt3 + WT3_ELEMS;

    // fp32 history staging lives in upper half of buf (disjoint from combined rows)
    float* hist = (float*)&buf[8192];          // 64 x 25 floats

#pragma unroll
    for (int i = 0; i < 6; ++i) {              // 1536 coalesced loads
        int e = tid + i * 256;
        int r = e / 24, cc = e - r * 24;
        hist[r * 25 + cc] = history[row0 * 24 + e];
    }
    __syncthreads();

    // combined[r][0..23] = bf16(history), [44..63] = 0 (pad vs poison-NaN)
#pragma unroll
    for (int i = 0; i < 6; ++i) {
        int e = tid + i * 256;
        int r = e / 24, cc = e - r * 24;
        buf[r * 72 + cc] = f2bf(hist[r * 25 + cc]);
    }
#pragma unroll
    for (int i = 0; i < 5; ++i) {
        int e = tid + i * 256;
        int r = e / 20, cc = e - r * 20;
        buf[r * 72 + 44 + cc] = 0;
    }
    // physics: one thread per row, 6-deep delay line, 20 unrolled steps
    if (tid < 64) {
        float pa = wsf[0], pb = wsf[1], pg = wsf[2];
        float d0 = hist[tid * 25 + 18], d1 = hist[tid * 25 + 19], d2 = hist[tid * 25 + 20];
        float d3 = hist[tid * 25 + 21], d4 = hist[tid * 25 + 22], d5 = hist[tid * 25 + 23];
        float T = d5;
#pragma unroll
        for (int s = 0; s < 20; ++s) {
            float t3 = T * T * T;
            float Tn = T - pa * T;
            Tn = Tn - pb * d0;
            Tn = Tn - pg * t3;
            tp[tid * 20 + s] = Tn;
            buf[tid * 72 + 24 + s] = f2bf(Tn);
            d0 = d1; d1 = d2; d2 = d3; d3 = d4; d4 = d5; d5 = Tn;
            T = Tn;
        }
    }
    __syncthreads();

    layer123<2, 72>(buf, wt1, eb1, w, c, q, lane);    // 44(pad64) -> 256
    layer123<8, 264>(buf, wt2, eb2, w, c, q, lane);   // 256 -> 256
    layer123<8, 264>(buf, wt3, cb1, w, c, q, lane);   // 256 -> 256

    // Layer 4: 256 -> 20 (pad 32). Each wave: its 16 samples (st = w), both ftiles.
    const v4u* wp4 = (const v4u*)wt4;
    v4u a4[2][8];
#pragma unroll
    for (int ft = 0; ft < 2; ++ft)
#pragma unroll
        for (int kt = 0; kt < 8; ++kt)
            a4[ft][kt] = wp4[(ft * 8 + kt) * 64 + lane];
    v4f acc0 = {0.0f, 0.0f, 0.0f, 0.0f}, acc1 = {0.0f, 0.0f, 0.0f, 0.0f};
#pragma unroll
    for (int kt = 0; kt < 8; ++kt) {
        v4u braw = *(const v4u*)&buf[(w * 16 + c) * 264 + kt * 32 + q * 8];
        v8bf bb = __builtin_bit_cast(v8bf, braw);
        acc0 = __builtin_amdgcn_mfma_f32_16x16x32_bf16(__builtin_bit_cast(v8bf, a4[0][kt]), bb, acc0, 0, 0, 0);
        acc1 = __builtin_amdgcn_mfma_f32_16x16x32_bf16(__builtin_bit_cast(v8bf, a4[1][kt]), bb, acc1, 0, 0, 0);
    }

    const float lam = wsf[3];
    const long sample = (long)row0 + w * 16 + c;
    float* outP = out;                         // T_pred
    float* outF = out + (long)NROWS * 20;      // T_physics
    float* outS = out + (long)NROWS * 40;      // T_soft
    {   // features q*4 .. q*4+3 (ftile 0: all valid, 0..15 < 20)
        v4f bi  = *(const v4f*)&cb2[q * 4];
        v4f tph = *(const v4f*)&tp[(w * 16 + c) * 20 + q * 4];
        v4f ts, pr;
#pragma unroll
        for (int r = 0; r < 4; ++r) {
            ts[r] = acc0[r] + bi[r];
            pr[r] = tph[r] + lam * ts[r];
        }
        *(v4f*)&outS[sample * 20 + q * 4] = ts;
        *(v4f*)&outP[sample * 20 + q * 4] = pr;
        *(v4f*)&outF[sample * 20 + q * 4] = tph;
    }
    if (q == 0) {  // ftile 1: only features 16..19 valid (q==0 rows)
        v4f bi  = *(const v4f*)&cb2[16];
        v4f tph = *(const v4f*)&tp[(w * 16 + c) * 20 + 16];
        v4f ts, pr;
#pragma unroll
        for (int r = 0; r < 4; ++r) {
            ts[r] = acc1[r] + bi[r];
            pr[r] = tph[r] + lam * ts[r];
        }
        *(v4f*)&outS[sample * 20 + 16] = ts;
        *(v4f*)&outP[sample * 20 + 16] = pr;
        *(v4f*)&outF[sample * 20 + 16] = tph;
    }
}

extern "C" void kernel_launch(void* const* d_in, const int* in_sizes, int n_in,
                              void* d_out, int out_size, void* d_ws, size_t ws_size,
                              hipStream_t stream)
{
    const float* history = (const float*)d_in[0];
    const float* enc_w1  = (const float*)d_in[1];
    const float* enc_b1  = (const float*)d_in[2];
    const float* enc_w2  = (const float*)d_in[3];
    const float* enc_b2  = (const float*)d_in[4];
    const float* cor_w1  = (const float*)d_in[5];
    const float* cor_b1  = (const float*)d_in[6];
    const float* cor_w2  = (const float*)d_in[7];
    const float* cor_b2  = (const float*)d_in[8];
    const float* alpha   = (const float*)d_in[9];
    const float* beta    = (const float*)d_in[10];
    const float* gamma   = (const float*)d_in[11];
    /* d_in[12] = tau, unused (TAU_INT compile-time) */
    const float* lmix    = (const float*)d_in[13];

    prep_kernel<<<609, 256, 0, stream>>>(enc_w1, enc_w2, cor_w1, cor_w2,
                                         alpha, beta, gamma, lmix,
                                         (unsigned char*)d_ws);
    fused_kernel<<<NROWS / 64, 256, 0, stream>>>(history, enc_b1, enc_b2, cor_b1, cor_b2,
                                                 (const unsigned char*)d_ws, (float*)d_out);
}

// Round 2
// 216.556 us; speedup vs baseline: 1.0159x; 1.0159x over previous
//
#include <hip/hip_runtime.h>
#include <hip/hip_bf16.h>

// Problem constants
#define NROWS 262144
#define HISTC 24
#define FOREC 20

// MFMA fragment vector types (gfx950 16x16x32 bf16: v8bf16 in, v4f32 acc)
typedef __bf16        v8bf __attribute__((ext_vector_type(8)));
typedef float         v4f  __attribute__((ext_vector_type(4)));
typedef unsigned int  v4u  __attribute__((ext_vector_type(4)));
typedef unsigned int  v2u  __attribute__((ext_vector_type(2)));

// Workspace layout (bytes): [0..16) scalars a,b,g,lam ; then swizzled bf16 weights.
// Swizzle: block (ntile,ktile) of 64 lanes x 8 bf16, elem ((nt*KT+kt)*64 + lane)*8 + j
// holding W^T[feat = nt*16 + (lane&15)][k = kt*32 + (lane>>4)*8 + j]  (OOB -> 0).
#define WS_WT1_OFF 64
#define WT1_ELEMS 16384   /* 16 nt * 2 kt * 512 */
#define WT2_ELEMS 65536   /* 16 nt * 8 kt * 512 */
#define WT3_ELEMS 65536
#define WT4_ELEMS 8192    /*  2 nt * 8 kt * 512 */

__device__ __forceinline__ unsigned short f2bf(float x) {
    unsigned u = __builtin_bit_cast(unsigned, x);
    u += 0x7FFFu + ((u >> 16) & 1u);          // round-to-nearest-even
    return (unsigned short)(u >> 16);
}

__device__ __forceinline__ unsigned pack2bf(float a, float b) {
    unsigned ua = __builtin_bit_cast(unsigned, a);
    unsigned ub = __builtin_bit_cast(unsigned, b);
    ua += 0x7FFFu + ((ua >> 16) & 1u);
    ub += 0x7FFFu + ((ub >> 16) & 1u);
    return (ua >> 16) | (ub & 0xFFFF0000u);
}

// tanh(x) = 1 - 2/(exp2(2*log2e*x)+1); v_exp_f32 + v_rcp_f32, ~1e-6 abs err
__device__ __forceinline__ float fast_tanh(float x) {
    float t = x * 2.885390081777927f;
    float p = __builtin_amdgcn_exp2f(t);
    float r = __builtin_amdgcn_rcpf(p + 1.0f);
    return __builtin_fmaf(-2.0f, r, 1.0f);
}

// ---------------- prep: scalars + weight transpose/convert/swizzle ----------------
// 8 elems per thread: 16B coalesced stores; reads coalesce over feat within 16-lane
// segments. 19456 worker threads = 76 blocks; block 76 does the 4 scalars.
__global__ void prep_kernel(const float* __restrict__ w1, const float* __restrict__ w2,
                            const float* __restrict__ w3, const float* __restrict__ w4,
                            const float* __restrict__ alpha, const float* __restrict__ beta,
                            const float* __restrict__ gamma, const float* __restrict__ lmix,
                            unsigned char* __restrict__ ws)
{
    if (blockIdx.x == 76) {                     // scalar block
        int t = threadIdx.x;
        float* wsf = (float*)ws;
        if (t == 0) wsf[0] = 1.0f / (1.0f + expf(-alpha[0]));
        else if (t == 1) wsf[1] = 1.0f / (1.0f + expf(-beta[0]));
        else if (t == 2) wsf[2] = fabsf(gamma[0]);
        else if (t == 3) wsf[3] = 1.0f / (1.0f + expf(-lmix[0]));
        return;
    }
    int idx = (blockIdx.x * 256 + threadIdx.x) * 8;   // elem base, 8 per thread
    const float* src;
    int KT, Kreal, Nreal, srcN, local;
    unsigned short* dst = (unsigned short*)(ws + WS_WT1_OFF);
    if (idx < WT1_ELEMS) {
        local = idx; src = w1; KT = 2; Kreal = 44; Nreal = 256; srcN = 256;
    } else if (idx < WT1_ELEMS + WT2_ELEMS) {
        local = idx - WT1_ELEMS; dst += WT1_ELEMS;
        src = w2; KT = 8; Kreal = 256; Nreal = 256; srcN = 256;
    } else if (idx < WT1_ELEMS + WT2_ELEMS + WT3_ELEMS) {
        local = idx - (WT1_ELEMS + WT2_ELEMS); dst += WT1_ELEMS + WT2_ELEMS;
        src = w3; KT = 8; Kreal = 256; Nreal = 256; srcN = 256;
    } else {
        local = idx - (WT1_ELEMS + WT2_ELEMS + WT3_ELEMS);
        dst += WT1_ELEMS + WT2_ELEMS + WT3_ELEMS;
        src = w4; KT = 8; Kreal = 256; Nreal = 20; srcN = 20;
    }
    int L   = (local >> 3) & 63;
    int blk = local >> 9;
    int kt = blk % KT, nt = blk / KT;
    int cc = L & 15,  qq = L >> 4;
    int feat = nt * 16 + cc;
    int kbase = kt * 32 + qq * 8;
    unsigned short tmp[8];
#pragma unroll
    for (int j = 0; j < 8; ++j) {
        int k = kbase + j;
        float v = (k < Kreal && feat < Nreal) ? src[k * srcN + feat] : 0.0f;
        tmp[j] = f2bf(v);
    }
    v4u pk;
    pk[0] = tmp[0] | ((unsigned)tmp[1] << 16);
    pk[1] = tmp[2] | ((unsigned)tmp[3] << 16);
    pk[2] = tmp[4] | ((unsigned)tmp[5] << 16);
    pk[3] = tmp[6] | ((unsigned)tmp[7] << 16);
    *(v4u*)&dst[local] = pk;
}

// ---------------- fused main kernel ----------------
// Transposed compute Y^T = W^T X^T: A-operand = weight frags streamed from L2
// (kt-outer, only 4 frags live -> low reg pressure), B-operand = activations
// from LDS [sample][feature] (stride 264). 8 waves/block; wave w owns features
// [w*32, w*32+32) (2 ftiles) x all 64 samples (4 stiles). acc = 32 regs.
// Target <=128 unified regs -> 4 waves/SIMD (16 waves/CU), 2x round-1 occupancy.
template<int KT, int SIN>
__device__ __forceinline__ void layer123(unsigned short* buf,
        const unsigned short* __restrict__ wsw, const float* __restrict__ bias,
        int w, int c, int q, int lane)
{
    const v4u* wp = (const v4u*)wsw;
    v4f acc[2][4];
#pragma unroll
    for (int ft = 0; ft < 2; ++ft)
#pragma unroll
        for (int st = 0; st < 4; ++st) {
            v4f z = {0.0f, 0.0f, 0.0f, 0.0f};
            acc[ft][st] = z;
        }

#pragma unroll 2
    for (int kt = 0; kt < KT; ++kt) {
        v4u a0 = wp[((w * 2 + 0) * KT + kt) * 64 + lane];
        v4u a1 = wp[((w * 2 + 1) * KT + kt) * 64 + lane];
#pragma unroll
        for (int st = 0; st < 4; ++st) {
            v4u braw = *(const v4u*)&buf[(st * 16 + c) * SIN + kt * 32 + q * 8];
            v8bf bb = __builtin_bit_cast(v8bf, braw);
            acc[0][st] = __builtin_amdgcn_mfma_f32_16x16x32_bf16(
                __builtin_bit_cast(v8bf, a0), bb, acc[0][st], 0, 0, 0);
            acc[1][st] = __builtin_amdgcn_mfma_f32_16x16x32_bf16(
                __builtin_bit_cast(v8bf, a1), bb, acc[1][st], 0, 0, 0);
        }
    }

    __syncthreads();   // all reads done before in-place overwrite

    // Epilogue: C layout -> lane (q,c) holds sample c, features (tile base)+q*4..+3.
    // Pack bf16 pairs, ds_write_b64 into [sample][feature].
#pragma unroll
    for (int ft = 0; ft < 2; ++ft) {
        v4f bi = *(const v4f*)&bias[w * 32 + ft * 16 + q * 4];
#pragma unroll
        for (int st = 0; st < 4; ++st) {
            float x0 = fast_tanh(acc[ft][st][0] + bi[0]);
            float x1 = fast_tanh(acc[ft][st][1] + bi[1]);
            float x2 = fast_tanh(acc[ft][st][2] + bi[2]);
            float x3 = fast_tanh(acc[ft][st][3] + bi[3]);
            v2u d; d[0] = pack2bf(x0, x1); d[1] = pack2bf(x2, x3);
            *(v2u*)&buf[(st * 16 + c) * 264 + w * 32 + ft * 16 + q * 4] = d;
        }
    }
    __syncthreads();
}

__global__ __launch_bounds__(512, 4) void fused_kernel(
    const float* __restrict__ history,
    const float* __restrict__ eb1, const float* __restrict__ eb2,
    const float* __restrict__ cb1, const float* __restrict__ cb2,
    const unsigned char* __restrict__ ws, float* __restrict__ out)
{
    __shared__ unsigned short buf[64 * 264];   // 33792 B, in-place act buffer
    __shared__ float tp[64 * 20];              // 5120 B fp32 T_physics

    const int tid  = threadIdx.x;
    const int w    = tid >> 6;                 // 8 waves
    const int lane = tid & 63;
    const int c    = lane & 15;
    const int q    = lane >> 4;
    const int row0 = blockIdx.x << 6;          // 64 samples per WG
    const float* wsf = (const float*)ws;
    const unsigned short* wt1 = (const unsigned short*)(ws + WS_WT1_OFF);
    const unsigned short* wt2 = wt1 + WT1_ELEMS;
    const unsigned short* wt3 = wt2 + WT2_ELEMS;
    const unsigned short* wt4 = wt3 + WT3_ELEMS;

    // fp32 history staging lives in upper half of buf (disjoint from combined rows)
    float* hist = (float*)&buf[8192];          // 64 x 25 floats

#pragma unroll
    for (int i = 0; i < 3; ++i) {              // 1536 coalesced loads
        int e = tid + i * 512;
        int r = e / 24, cc = e - r * 24;
        hist[r * 25 + cc] = history[row0 * 24 + e];
    }
    __syncthreads();

    // combined[r][0..23] = bf16(history), [44..63] = 0 (pad vs poison-NaN)
#pragma unroll
    for (int i = 0; i < 3; ++i) {
        int e = tid + i * 512;
        int r = e / 24, cc = e - r * 24;
        buf[r * 72 + cc] = f2bf(hist[r * 25 + cc]);
    }
#pragma unroll
    for (int i = 0; i < 3; ++i) {
        int e = tid + i * 512;
        if (e < 1280) {
            int r = e / 20, cc = e - r * 20;
            buf[r * 72 + 44 + cc] = 0;
        }
    }
    // physics: one thread per row, 6-deep delay line, 20 unrolled steps
    if (tid < 64) {
        float pa = wsf[0], pb = wsf[1], pg = wsf[2];
        float d0 = hist[tid * 25 + 18], d1 = hist[tid * 25 + 19], d2 = hist[tid * 25 + 20];
        float d3 = hist[tid * 25 + 21], d4 = hist[tid * 25 + 22], d5 = hist[tid * 25 + 23];
        float T = d5;
#pragma unroll
        for (int s = 0; s < 20; ++s) {
            float t3 = T * T * T;
            float Tn = T - pa * T;
            Tn = Tn - pb * d0;
            Tn = Tn - pg * t3;
            tp[tid * 20 + s] = Tn;
            buf[tid * 72 + 24 + s] = f2bf(Tn);
            d0 = d1; d1 = d2; d2 = d3; d3 = d4; d4 = d5; d5 = Tn;
            T = Tn;
        }
    }
    __syncthreads();

    layer123<2, 72>(buf, wt1, eb1, w, c, q, lane);    // 44(pad64) -> 256
    layer123<8, 264>(buf, wt2, eb2, w, c, q, lane);   // 256 -> 256
    layer123<8, 264>(buf, wt3, cb1, w, c, q, lane);   // 256 -> 256

    // Layer 4: 256 -> 20 (2 ftiles x 4 stiles = 8 tiles = 1 tile per wave).
    const int ft4 = w >> 2;                    // 0..1
    const int st4 = w & 3;                     // 0..3
    const v4u* wp4 = (const v4u*)wt4;
    v4f acc4 = {0.0f, 0.0f, 0.0f, 0.0f};
#pragma unroll 2
    for (int kt = 0; kt < 8; ++kt) {
        v4u a = wp4[(ft4 * 8 + kt) * 64 + lane];
        v4u braw = *(const v4u*)&buf[(st4 * 16 + c) * 264 + kt * 32 + q * 8];
        v8bf bb = __builtin_bit_cast(v8bf, braw);
        acc4 = __builtin_amdgcn_mfma_f32_16x16x32_bf16(
            __builtin_bit_cast(v8bf, a), bb, acc4, 0, 0, 0);
    }

    const float lam = wsf[3];
    const long sample = (long)row0 + st4 * 16 + c;
    float* outP = out;                         // T_pred
    float* outF = out + (long)NROWS * 20;      // T_physics
    float* outS = out + (long)NROWS * 40;      // T_soft
    const int f0 = ft4 * 16 + q * 4;           // feature base this lane holds
    if (f0 < 20) {                             // ft4==1 valid only for q==0
        v4f bi  = *(const v4f*)&cb2[f0];
        v4f tph = *(const v4f*)&tp[(st4 * 16 + c) * 20 + f0];
        v4f ts, pr;
#pragma unroll
        for (int r = 0; r < 4; ++r) {
            ts[r] = acc4[r] + bi[r];
            pr[r] = tph[r] + lam * ts[r];
        }
        *(v4f*)&outS[sample * 20 + f0] = ts;
        *(v4f*)&outP[sample * 20 + f0] = pr;
        *(v4f*)&outF[sample * 20 + f0] = tph;
    }
}

extern "C" void kernel_launch(void* const* d_in, const int* in_sizes, int n_in,
                              void* d_out, int out_size, void* d_ws, size_t ws_size,
                              hipStream_t stream)
{
    const float* history = (const float*)d_in[0];
    const float* enc_w1  = (const float*)d_in[1];
    const float* enc_b1  = (const float*)d_in[2];
    const float* enc_w2  = (const float*)d_in[3];
    const float* enc_b2  = (const float*)d_in[4];
    const float* cor_w1  = (const float*)d_in[5];
    const float* cor_b1  = (const float*)d_in[6];
    const float* cor_w2  = (const float*)d_in[7];
    const float* cor_b2  = (const float*)d_in[8];
    const float* alpha   = (const float*)d_in[9];
    const float* beta    = (const float*)d_in[10];
    const float* gamma   = (const float*)d_in[11];
    /* d_in[12] = tau, unused (TAU_INT compile-time) */
    const float* lmix    = (const float*)d_in[13];

    prep_kernel<<<77, 256, 0, stream>>>(enc_w1, enc_w2, cor_w1, cor_w2,
                                        alpha, beta, gamma, lmix,
                                        (unsigned char*)d_ws);
    fused_kernel<<<NROWS / 64, 512, 0, stream>>>(history, enc_b1, enc_b2, cor_b1, cor_b2,
                                                 (const unsigned char*)d_ws, (float*)d_out);
}

// Round 3
// 210.949 us; speedup vs baseline: 1.0429x; 1.0266x over previous
//
#include <hip/hip_runtime.h>
#include <hip/hip_bf16.h>

// Problem constants
#define NROWS 262144
#define HISTC 24
#define FOREC 20

// MFMA fragment vector types (gfx950 16x16x32 bf16: v8bf16 in, v4f32 acc)
typedef __bf16        v8bf __attribute__((ext_vector_type(8)));
typedef float         v4f  __attribute__((ext_vector_type(4)));
typedef float         v2f  __attribute__((ext_vector_type(2)));
typedef unsigned int  v4u  __attribute__((ext_vector_type(4)));
typedef unsigned int  v2u  __attribute__((ext_vector_type(2)));

// Workspace layout (bytes): [0..16) scalars a,b,g,lam ; then swizzled bf16 weights.
// Swizzle: block (ntile,ktile) of 64 lanes x 8 bf16, elem ((nt*KT+kt)*64 + lane)*8 + j
// holding W^T[feat = nt*16 + (lane&15)][k = kt*32 + (lane>>4)*8 + j]  (OOB -> 0).
#define WS_WT1_OFF 64
#define WT1_ELEMS 16384   /* 16 nt * 2 kt * 512 */
#define WT2_ELEMS 65536   /* 16 nt * 8 kt * 512 */
#define WT3_ELEMS 65536
#define WT4_ELEMS 8192    /*  2 nt * 8 kt * 512 */

__device__ __forceinline__ unsigned short f2bf(float x) {
    unsigned u = __builtin_bit_cast(unsigned, x);
    u += 0x7FFFu + ((u >> 16) & 1u);          // round-to-nearest-even
    return (unsigned short)(u >> 16);
}

__device__ __forceinline__ unsigned pack2bf(float a, float b) {
    unsigned ua = __builtin_bit_cast(unsigned, a);
    unsigned ub = __builtin_bit_cast(unsigned, b);
    ua += 0x7FFFu + ((ua >> 16) & 1u);
    ub += 0x7FFFu + ((ub >> 16) & 1u);
    return (ua >> 16) | (ub & 0xFFFF0000u);
}

// tanh(x) = 1 - 2/(exp2(2*log2e*x)+1); v_exp_f32 + v_rcp_f32, ~1e-6 abs err
__device__ __forceinline__ float fast_tanh(float x) {
    float t = x * 2.885390081777927f;
    float p = __builtin_amdgcn_exp2f(t);
    float r = __builtin_amdgcn_rcpf(p + 1.0f);
    return __builtin_fmaf(-2.0f, r, 1.0f);
}

// ---------------- prep: scalars + weight transpose/convert/swizzle ----------------
__global__ void prep_kernel(const float* __restrict__ w1, const float* __restrict__ w2,
                            const float* __restrict__ w3, const float* __restrict__ w4,
                            const float* __restrict__ alpha, const float* __restrict__ beta,
                            const float* __restrict__ gamma, const float* __restrict__ lmix,
                            unsigned char* __restrict__ ws)
{
    if (blockIdx.x == 76) {                     // scalar block
        int t = threadIdx.x;
        float* wsf = (float*)ws;
        if (t == 0) wsf[0] = 1.0f / (1.0f + expf(-alpha[0]));
        else if (t == 1) wsf[1] = 1.0f / (1.0f + expf(-beta[0]));
        else if (t == 2) wsf[2] = fabsf(gamma[0]);
        else if (t == 3) wsf[3] = 1.0f / (1.0f + expf(-lmix[0]));
        return;
    }
    int idx = (blockIdx.x * 256 + threadIdx.x) * 8;   // elem base, 8 per thread
    const float* src;
    int KT, Kreal, Nreal, srcN, local;
    unsigned short* dst = (unsigned short*)(ws + WS_WT1_OFF);
    if (idx < WT1_ELEMS) {
        local = idx; src = w1; KT = 2; Kreal = 44; Nreal = 256; srcN = 256;
    } else if (idx < WT1_ELEMS + WT2_ELEMS) {
        local = idx - WT1_ELEMS; dst += WT1_ELEMS;
        src = w2; KT = 8; Kreal = 256; Nreal = 256; srcN = 256;
    } else if (idx < WT1_ELEMS + WT2_ELEMS + WT3_ELEMS) {
        local = idx - (WT1_ELEMS + WT2_ELEMS); dst += WT1_ELEMS + WT2_ELEMS;
        src = w3; KT = 8; Kreal = 256; Nreal = 256; srcN = 256;
    } else {
        local = idx - (WT1_ELEMS + WT2_ELEMS + WT3_ELEMS);
        dst += WT1_ELEMS + WT2_ELEMS + WT3_ELEMS;
        src = w4; KT = 8; Kreal = 256; Nreal = 20; srcN = 20;
    }
    int L   = (local >> 3) & 63;
    int blk = local >> 9;
    int kt = blk % KT, nt = blk / KT;
    int cc = L & 15,  qq = L >> 4;
    int feat = nt * 16 + cc;
    int kbase = kt * 32 + qq * 8;
    unsigned short tmp[8];
#pragma unroll
    for (int j = 0; j < 8; ++j) {
        int k = kbase + j;
        float v = (k < Kreal && feat < Nreal) ? src[k * srcN + feat] : 0.0f;
        tmp[j] = f2bf(v);
    }
    v4u pk;
    pk[0] = tmp[0] | ((unsigned)tmp[1] << 16);
    pk[1] = tmp[2] | ((unsigned)tmp[3] << 16);
    pk[2] = tmp[4] | ((unsigned)tmp[5] << 16);
    pk[3] = tmp[6] | ((unsigned)tmp[7] << 16);
    *(v4u*)&dst[local] = pk;
}

// ---------------- fused main kernel ----------------
// 4 waves / 256 threads, 64 samples per block. Wave w owns 4 ftiles
// (features w*64..w*64+63) x 4 stiles (all 64 samples): each ds_read_b128
// B-fragment feeds 4 MFMAs (halves per-CU LDS read traffic vs 2ft variant).
// A-operand (weights) streamed kt-outer from L2 (4 live frags). acc = 64 AGPR.
template<int KT>
__device__ __forceinline__ void layer123(unsigned short* buf,
        const unsigned short* __restrict__ wsw, const float* __restrict__ bias,
        int w, int c, int q, int lane)
{
    const v4u* wp = (const v4u*)wsw;
    v4f acc[4][4];
#pragma unroll
    for (int ft = 0; ft < 4; ++ft)
#pragma unroll
        for (int st = 0; st < 4; ++st) {
            v4f z = {0.0f, 0.0f, 0.0f, 0.0f};
            acc[ft][st] = z;
        }

#pragma unroll 2
    for (int kt = 0; kt < KT; ++kt) {
        v4u a[4];
#pragma unroll
        for (int ft = 0; ft < 4; ++ft)
            a[ft] = wp[((w * 4 + ft) * KT + kt) * 64 + lane];
#pragma unroll
        for (int st = 0; st < 4; ++st) {
            v4u braw = *(const v4u*)&buf[(st * 16 + c) * 264 + kt * 32 + q * 8];
            v8bf bb = __builtin_bit_cast(v8bf, braw);
#pragma unroll
            for (int ft = 0; ft < 4; ++ft)
                acc[ft][st] = __builtin_amdgcn_mfma_f32_16x16x32_bf16(
                    __builtin_bit_cast(v8bf, a[ft]), bb, acc[ft][st], 0, 0, 0);
        }
    }

    __syncthreads();   // all reads done before in-place overwrite

    // Epilogue: C layout -> lane (q,c) holds sample c, features base+q*4..+3.
#pragma unroll
    for (int ft = 0; ft < 4; ++ft) {
        v4f bi = *(const v4f*)&bias[w * 64 + ft * 16 + q * 4];
#pragma unroll
        for (int st = 0; st < 4; ++st) {
            float x0 = fast_tanh(acc[ft][st][0] + bi[0]);
            float x1 = fast_tanh(acc[ft][st][1] + bi[1]);
            float x2 = fast_tanh(acc[ft][st][2] + bi[2]);
            float x3 = fast_tanh(acc[ft][st][3] + bi[3]);
            v2u d; d[0] = pack2bf(x0, x1); d[1] = pack2bf(x2, x3);
            *(v2u*)&buf[(st * 16 + c) * 264 + w * 64 + ft * 16 + q * 4] = d;
        }
    }
    __syncthreads();
}

__global__ __launch_bounds__(256, 4) void fused_kernel(
    const float* __restrict__ history,
    const float* __restrict__ eb1, const float* __restrict__ eb2,
    const float* __restrict__ cb1, const float* __restrict__ cb2,
    const unsigned char* __restrict__ ws, float* __restrict__ out)
{
    __shared__ unsigned short buf[64 * 264];   // 33792 B, in-place act buffer
    __shared__ float tp[64 * 20];              // 5120 B fp32 T_physics

    const int tid  = threadIdx.x;
    const int w    = tid >> 6;                 // 4 waves
    const int lane = tid & 63;
    const int c    = lane & 15;
    const int q    = lane >> 4;
    const int row0 = blockIdx.x << 6;          // 64 samples per WG
    const float* wsf = (const float*)ws;
    const unsigned short* wt1 = (const unsigned short*)(ws + WS_WT1_OFF);
    const unsigned short* wt2 = wt1 + WT1_ELEMS;
    const unsigned short* wt3 = wt2 + WT2_ELEMS;
    const unsigned short* wt4 = wt3 + WT3_ELEMS;

    // --- staging: global float4 -> bf16x4 pack in regs -> one ds_write_b64 ---
    // 64 rows x 6 float4-groups = 384 tasks; fully coalesced global reads.
#pragma unroll
    for (int i = 0; i < 2; ++i) {
        int e = tid + i * 256;
        if (e < 384) {
            int r  = e / 6, c4 = e - r * 6;
            v4f h4 = *(const v4f*)&history[(long)(row0 + r) * 24 + c4 * 4];
            v2u d; d[0] = pack2bf(h4[0], h4[1]); d[1] = pack2bf(h4[2], h4[3]);
            *(v2u*)&buf[r * 264 + c4 * 4] = d;
        }
    }
    // zero-fill cols 44..63 (pad vs poison): 64 rows x 5 b64-groups = 320 tasks
#pragma unroll
    for (int i = 0; i < 2; ++i) {
        int e = tid + i * 256;
        if (e < 320) {
            int r = e / 5, g = e - r * 5;
            v2u z = {0u, 0u};
            *(v2u*)&buf[r * 264 + 44 + g * 4] = z;
        }
    }
    // physics: one thread per row; last-6 history read direct from global (L2-hot)
    if (tid < 64) {
        const float* hrow = &history[(long)(row0 + tid) * 24];
        v2f h18 = *(const v2f*)&hrow[18];
        v4f h20 = *(const v4f*)&hrow[20];
        float pa = wsf[0], pb = wsf[1], pg = wsf[2];
        float d0 = h18[0], d1 = h18[1], d2 = h20[0];
        float d3 = h20[1], d4 = h20[2], d5 = h20[3];
        float T = d5;
#pragma unroll
        for (int s = 0; s < 20; ++s) {
            float t3 = T * T * T;
            float Tn = T - pa * T;
            Tn = Tn - pb * d0;
            Tn = Tn - pg * t3;
            tp[tid * 20 + s] = Tn;
            buf[tid * 264 + 24 + s] = f2bf(Tn);
            d0 = d1; d1 = d2; d2 = d3; d3 = d4; d4 = d5; d5 = Tn;
            T = Tn;
        }
    }
    __syncthreads();

    layer123<2>(buf, wt1, eb1, w, c, q, lane);    // 44(pad64) -> 256
    layer123<8>(buf, wt2, eb2, w, c, q, lane);    // 256 -> 256
    layer123<8>(buf, wt3, cb1, w, c, q, lane);    // 256 -> 256

    // Layer 4: 256 -> 20. Wave w = stile w; both ftiles share each B-read.
    const v4u* wp4 = (const v4u*)wt4;
    v4f acc40 = {0.0f, 0.0f, 0.0f, 0.0f}, acc41 = {0.0f, 0.0f, 0.0f, 0.0f};
#pragma unroll 2
    for (int kt = 0; kt < 8; ++kt) {
        v4u a0 = wp4[(0 * 8 + kt) * 64 + lane];
        v4u a1 = wp4[(1 * 8 + kt) * 64 + lane];
        v4u braw = *(const v4u*)&buf[(w * 16 + c) * 264 + kt * 32 + q * 8];
        v8bf bb = __builtin_bit_cast(v8bf, braw);
        acc40 = __builtin_amdgcn_mfma_f32_16x16x32_bf16(
            __builtin_bit_cast(v8bf, a0), bb, acc40, 0, 0, 0);
        acc41 = __builtin_amdgcn_mfma_f32_16x16x32_bf16(
            __builtin_bit_cast(v8bf, a1), bb, acc41, 0, 0, 0);
    }

    const float lam = wsf[3];
    const long sample = (long)row0 + w * 16 + c;
    float* outP = out;                         // T_pred
    float* outF = out + (long)NROWS * 20;      // T_physics
    float* outS = out + (long)NROWS * 40;      // T_soft
    {   // ftile 0: features q*4..q*4+3, all valid (<20)
        int f0 = q * 4;
        v4f bi  = *(const v4f*)&cb2[f0];
        v4f tph = *(const v4f*)&tp[(w * 16 + c) * 20 + f0];
        v4f ts, pr;
#pragma unroll
        for (int r = 0; r < 4; ++r) {
            ts[r] = acc40[r] + bi[r];
            pr[r] = tph[r] + lam * ts[r];
        }
        *(v4f*)&outS[sample * 20 + f0] = ts;
        *(v4f*)&outP[sample * 20 + f0] = pr;
        *(v4f*)&outF[sample * 20 + f0] = tph;
    }
    if (q == 0) {  // ftile 1: features 16..19 valid only for q==0
        v4f bi  = *(const v4f*)&cb2[16];
        v4f tph = *(const v4f*)&tp[(w * 16 + c) * 20 + 16];
        v4f ts, pr;
#pragma unroll
        for (int r = 0; r < 4; ++r) {
            ts[r] = acc41[r] + bi[r];
            pr[r] = tph[r] + lam * ts[r];
        }
        *(v4f*)&outS[sample * 20 + 16] = ts;
        *(v4f*)&outP[sample * 20 + 16] = pr;
        *(v4f*)&outF[sample * 20 + 16] = tph;
    }
}

extern "C" void kernel_launch(void* const* d_in, const int* in_sizes, int n_in,
                              void* d_out, int out_size, void* d_ws, size_t ws_size,
                              hipStream_t stream)
{
    const float* history = (const float*)d_in[0];
    const float* enc_w1  = (const float*)d_in[1];
    const float* enc_b1  = (const float*)d_in[2];
    const float* enc_w2  = (const float*)d_in[3];
    const float* enc_b2  = (const float*)d_in[4];
    const float* cor_w1  = (const float*)d_in[5];
    const float* cor_b1  = (const float*)d_in[6];
    const float* cor_w2  = (const float*)d_in[7];
    const float* cor_b2  = (const float*)d_in[8];
    const float* alpha   = (const float*)d_in[9];
    const float* beta    = (const float*)d_in[10];
    const float* gamma   = (const float*)d_in[11];
    /* d_in[12] = tau, unused (TAU_INT compile-time) */
    const float* lmix    = (const float*)d_in[13];

    prep_kernel<<<77, 256, 0, stream>>>(enc_w1, enc_w2, cor_w1, cor_w2,
                                        alpha, beta, gamma, lmix,
                                        (unsigned char*)d_ws);
    fused_kernel<<<NROWS / 64, 256, 0, stream>>>(history, enc_b1, enc_b2, cor_b1, cor_b2,
                                                 (const unsigned char*)d_ws, (float*)d_out);
}

// Round 5
// 207.257 us; speedup vs baseline: 1.0614x; 1.0178x over previous
//
#include <hip/hip_runtime.h>
#include <hip/hip_bf16.h>

// Problem constants
#define NROWS 262144
#define HISTC 24
#define FOREC 20

// MFMA fragment vector types (gfx950 16x16x32 bf16: v8bf16 in, v4f32 acc)
typedef __bf16        v8bf __attribute__((ext_vector_type(8)));
typedef float         v4f  __attribute__((ext_vector_type(4)));
typedef float         v2f  __attribute__((ext_vector_type(2)));
typedef unsigned int  v4u  __attribute__((ext_vector_type(4)));
typedef unsigned int  v2u  __attribute__((ext_vector_type(2)));

// Workspace layout (bytes): [0..16) scalars a,b,g,lam ; then swizzled bf16 weights.
// Swizzle: block (ntile,ktile) of 64 lanes x 8 bf16, elem ((nt*KT+kt)*64 + lane)*8 + j
// holding W^T[feat = nt*16 + (lane&15)][k = kt*32 + (lane>>4)*8 + j]  (OOB -> 0).
// WT4 is REPLICATED to 16 nt-slots (real nt = slot&1) so the generic cross-layer
// prefetch index ((w*4+ft)*8+kt) is valid for layer 4 too.
#define WS_WT1_OFF 64
#define WT1_ELEMS 16384    /* 16 nt * 2 kt * 512 */
#define WT2_ELEMS 65536    /* 16 nt * 8 kt * 512 */
#define WT3_ELEMS 65536
#define WT4R_ELEMS 65536   /* 16 nt-slots (real nt = slot&1) * 8 kt * 512 */

__device__ __forceinline__ unsigned short f2bf(float x) {
    unsigned u = __builtin_bit_cast(unsigned, x);
    u += 0x7FFFu + ((u >> 16) & 1u);          // round-to-nearest-even
    return (unsigned short)(u >> 16);
}

__device__ __forceinline__ unsigned packbf2(float a, float b) {
    unsigned ua = __builtin_bit_cast(unsigned, a);
    unsigned ub = __builtin_bit_cast(unsigned, b);
    ua += 0x7FFFu + ((ua >> 16) & 1u);        // RNE, matches f2bf
    ub += 0x7FFFu + ((ub >> 16) & 1u);
    return (ua >> 16) | (ub & 0xFFFF0000u);
}

// tanh(x) = 1 - 2/(exp2(2*log2e*x)+1); v_exp_f32 + v_rcp_f32, ~1e-6 abs err
__device__ __forceinline__ float fast_tanh(float x) {
    float t = x * 2.885390081777927f;
    float p = __builtin_amdgcn_exp2f(t);
    float r = __builtin_amdgcn_rcpf(p + 1.0f);
    return __builtin_fmaf(-2.0f, r, 1.0f);
}

// ---------------- prep: scalars + weight transpose/convert/swizzle ----------------
// 8 elems/thread, 16B stores. 212992 elems = 104 blocks; block 104 does scalars.
__global__ void prep_kernel(const float* __restrict__ w1, const float* __restrict__ w2,
                            const float* __restrict__ w3, const float* __restrict__ w4,
                            const float* __restrict__ alpha, const float* __restrict__ beta,
                            const float* __restrict__ gamma, const float* __restrict__ lmix,
                            unsigned char* __restrict__ ws)
{
    if (blockIdx.x == 104) {                    // scalar block
        int t = threadIdx.x;
        float* wsf = (float*)ws;
        if (t == 0) wsf[0] = 1.0f / (1.0f + expf(-alpha[0]));
        else if (t == 1) wsf[1] = 1.0f / (1.0f + expf(-beta[0]));
        else if (t == 2) wsf[2] = fabsf(gamma[0]);
        else if (t == 3) wsf[3] = 1.0f / (1.0f + expf(-lmix[0]));
        return;
    }
    int idx = (blockIdx.x * 256 + threadIdx.x) * 8;   // elem base, 8 per thread
    const float* src;
    int KT, Kreal, Nreal, srcN, local, ntmask;
    unsigned short* dst = (unsigned short*)(ws + WS_WT1_OFF);
    if (idx < WT1_ELEMS) {
        local = idx; src = w1; KT = 2; Kreal = 44; Nreal = 256; srcN = 256; ntmask = 255;
    } else if (idx < WT1_ELEMS + WT2_ELEMS) {
        local = idx - WT1_ELEMS; dst += WT1_ELEMS;
        src = w2; KT = 8; Kreal = 256; Nreal = 256; srcN = 256; ntmask = 255;
    } else if (idx < WT1_ELEMS + WT2_ELEMS + WT3_ELEMS) {
        local = idx - (WT1_ELEMS + WT2_ELEMS); dst += WT1_ELEMS + WT2_ELEMS;
        src = w3; KT = 8; Kreal = 256; Nreal = 256; srcN = 256; ntmask = 255;
    } else {
        local = idx - (WT1_ELEMS + WT2_ELEMS + WT3_ELEMS);
        dst += WT1_ELEMS + WT2_ELEMS + WT3_ELEMS;
        src = w4; KT = 8; Kreal = 256; Nreal = 20; srcN = 20; ntmask = 1;  // replicate
    }
    int L   = (local >> 3) & 63;
    int blk = local >> 9;
    int kt = blk % KT, nt = (blk / KT) & ntmask;
    int cc = L & 15,  qq = L >> 4;
    int feat = nt * 16 + cc;
    int kbase = kt * 32 + qq * 8;
    unsigned short tmp[8];
#pragma unroll
    for (int j = 0; j < 8; ++j) {
        int k = kbase + j;
        float v = (k < Kreal && feat < Nreal) ? src[k * srcN + feat] : 0.0f;
        tmp[j] = f2bf(v);
    }
    v4u pk;
    pk[0] = tmp[0] | ((unsigned)tmp[1] << 16);
    pk[1] = tmp[2] | ((unsigned)tmp[3] << 16);
    pk[2] = tmp[4] | ((unsigned)tmp[5] << 16);
    pk[3] = tmp[6] | ((unsigned)tmp[7] << 16);
    *(v4u*)&dst[local] = pk;
}

// ---------------- fused main kernel ----------------
// 4 waves, 64 samples/block. Wave w: 4 ftiles (features w*64..+63) x 4 stiles.
// Weight frags software-pipelined 2-deep through a 3-slot rotating buffer A[3][4];
// the last two kt iterations prefetch the NEXT layer's kt0/kt1, so those loads are
// in flight across the epilogue tanh + both barriers (never drain vmcnt at a use).
// S0 = rotation phase on entry (compile-time); exit phase = (S0+KT)%3.
template<int KT, int KTN, int S0>
__device__ __forceinline__ void layer_pipe(unsigned short* buf,
        const v4u* __restrict__ wp, const v4u* __restrict__ wpn,
        const float* __restrict__ bias, v4u A[3][4],
        int w, int c, int q, int lane)
{
    v4f acc[4][4];
#pragma unroll
    for (int ft = 0; ft < 4; ++ft)
#pragma unroll
        for (int st = 0; st < 4; ++st) {
            v4f z = {0.0f, 0.0f, 0.0f, 0.0f};
            acc[ft][st] = z;
        }

#pragma unroll
    for (int kt = 0; kt < KT; ++kt) {
        const int cs = (S0 + kt) % 3;
        const int ps = (S0 + kt + 2) % 3;
        if (kt + 2 < KT) {
#pragma unroll
            for (int ft = 0; ft < 4; ++ft)
                A[ps][ft] = wp[((w * 4 + ft) * KT + kt + 2) * 64 + lane];
        } else {
#pragma unroll
            for (int ft = 0; ft < 4; ++ft)
                A[ps][ft] = wpn[((w * 4 + ft) * KTN + (kt + 2 - KT)) * 64 + lane];
        }
#pragma unroll
        for (int st = 0; st < 4; ++st) {
            v4u braw = *(const v4u*)&buf[(st * 16 + c) * 264 + kt * 32 + q * 8];
            v8bf bb = __builtin_bit_cast(v8bf, braw);
#pragma unroll
            for (int ft = 0; ft < 4; ++ft)
                acc[ft][st] = __builtin_amdgcn_mfma_f32_16x16x32_bf16(
                    __builtin_bit_cast(v8bf, A[cs][ft]), bb, acc[ft][st], 0, 0, 0);
        }
    }

    __syncthreads();   // all reads done before in-place overwrite

    // Epilogue: lane (q,c) holds sample c, features base+q*4..+3 per tile.
#pragma unroll
    for (int ft = 0; ft < 4; ++ft) {
        v4f bi = *(const v4f*)&bias[w * 64 + ft * 16 + q * 4];
#pragma unroll
        for (int st = 0; st < 4; ++st) {
            float x0 = fast_tanh(acc[ft][st][0] + bi[0]);
            float x1 = fast_tanh(acc[ft][st][1] + bi[1]);
            float x2 = fast_tanh(acc[ft][st][2] + bi[2]);
            float x3 = fast_tanh(acc[ft][st][3] + bi[3]);
            v2u d; d[0] = packbf2(x0, x1); d[1] = packbf2(x2, x3);
            *(v2u*)&buf[(st * 16 + c) * 264 + w * 64 + ft * 16 + q * 4] = d;
        }
    }
    __syncthreads();
}

__global__ __launch_bounds__(256, 3) void fused_kernel(
    const float* __restrict__ history,
    const float* __restrict__ eb1, const float* __restrict__ eb2,
    const float* __restrict__ cb1, const float* __restrict__ cb2,
    const unsigned char* __restrict__ ws, float* __restrict__ out)
{
    __shared__ unsigned short buf[64 * 264];   // 33792 B, in-place act buffer
    __shared__ float tp[64 * 20];              // 5120 B fp32 T_physics

    const int tid  = threadIdx.x;
    const int w    = tid >> 6;                 // 4 waves
    const int lane = tid & 63;
    const int c    = lane & 15;
    const int q    = lane >> 4;
    const int row0 = blockIdx.x << 6;          // 64 samples per WG
    const float* wsf = (const float*)ws;
    const v4u* wp1 = (const v4u*)(ws + WS_WT1_OFF);
    const v4u* wp2 = wp1 + WT1_ELEMS / 8;
    const v4u* wp3 = wp2 + WT2_ELEMS / 8;
    const v4u* wp4 = wp3 + WT3_ELEMS / 8;

    // Preload layer-1 weight frags (kt0 -> slot0, kt1 -> slot1) BEFORE staging,
    // so the L2 round-trip overlaps the history load + physics.
    v4u A[3][4];
#pragma unroll
    for (int ft = 0; ft < 4; ++ft) {
        A[0][ft] = wp1[((w * 4 + ft) * 2 + 0) * 64 + lane];
        A[1][ft] = wp1[((w * 4 + ft) * 2 + 1) * 64 + lane];
    }

    // --- staging: global float4 -> bf16x4 pack in regs -> one ds_write_b64 ---
#pragma unroll
    for (int i = 0; i < 2; ++i) {
        int e = tid + i * 256;
        if (e < 384) {
            int r  = e / 6, c4 = e - r * 6;
            v4f h4 = *(const v4f*)&history[(long)(row0 + r) * 24 + c4 * 4];
            v2u d; d[0] = packbf2(h4[0], h4[1]); d[1] = packbf2(h4[2], h4[3]);
            *(v2u*)&buf[r * 264 + c4 * 4] = d;
        }
    }
    // zero-fill cols 44..63 (pad vs poison): 64 rows x 5 b64-groups = 320 tasks
#pragma unroll
    for (int i = 0; i < 2; ++i) {
        int e = tid + i * 256;
        if (e < 320) {
            int r = e / 5, g = e - r * 5;
            v2u z = {0u, 0u};
            *(v2u*)&buf[r * 264 + 44 + g * 4] = z;
        }
    }
    // physics: one thread per row; last-6 history read direct from global (L2-hot)
    if (tid < 64) {
        const float* hrow = &history[(long)(row0 + tid) * 24];
        v2f h18 = *(const v2f*)&hrow[18];
        v4f h20 = *(const v4f*)&hrow[20];
        float pa = wsf[0], pb = wsf[1], pg = wsf[2];
        float d0 = h18[0], d1 = h18[1], d2 = h20[0];
        float d3 = h20[1], d4 = h20[2], d5 = h20[3];
        float T = d5;
#pragma unroll
        for (int s = 0; s < 20; ++s) {
            float t3 = T * T * T;
            float Tn = T - pa * T;
            Tn = Tn - pb * d0;
            Tn = Tn - pg * t3;
            tp[tid * 20 + s] = Tn;
            buf[tid * 264 + 24 + s] = f2bf(Tn);
            d0 = d1; d1 = d2; d2 = d3; d3 = d4; d4 = d5; d5 = Tn;
            T = Tn;
        }
    }
    __syncthreads();

    // Rotation phases: L1 S0=0 (KT=2) -> L2 S0=2 (KT=8) -> L3 S0=1 -> L4 S0=0.
    layer_pipe<2, 8, 0>(buf, wp1, wp2, eb1, A, w, c, q, lane);   // 44(pad64)->256
    layer_pipe<8, 8, 2>(buf, wp2, wp3, eb2, A, w, c, q, lane);   // 256->256
    layer_pipe<8, 8, 1>(buf, wp3, wp4, cb1, A, w, c, q, lane);   // 256->256

    // Layer 4: 256 -> 20. Wave w = stile w; A[0][0..1]/A[1][0..1] hold kt0/kt1
    // (replicated wt4: slot w*4+ft, real nt = ft for ft<2).
    v4f acc40 = {0.0f, 0.0f, 0.0f, 0.0f}, acc41 = {0.0f, 0.0f, 0.0f, 0.0f};
#pragma unroll
    for (int kt = 0; kt < 8; ++kt) {
        const int cs = kt % 3, ps = (kt + 2) % 3;
        if (kt + 2 < 8) {
            A[ps][0] = wp4[((w * 4 + 0) * 8 + kt + 2) * 64 + lane];
            A[ps][1] = wp4[((w * 4 + 1) * 8 + kt + 2) * 64 + lane];
        }
        v4u braw = *(const v4u*)&buf[(w * 16 + c) * 264 + kt * 32 + q * 8];
        v8bf bb = __builtin_bit_cast(v8bf, braw);
        acc40 = __builtin_amdgcn_mfma_f32_16x16x32_bf16(
            __builtin_bit_cast(v8bf, A[cs][0]), bb, acc40, 0, 0, 0);
        acc41 = __builtin_amdgcn_mfma_f32_16x16x32_bf16(
            __builtin_bit_cast(v8bf, A[cs][1]), bb, acc41, 0, 0, 0);
    }

    const float lam = wsf[3];
    const long sample = (long)row0 + w * 16 + c;
    float* outP = out;                         // T_pred
    float* outF = out + (long)NROWS * 20;      // T_physics
    float* outS = out + (long)NROWS * 40;      // T_soft
    {   // ftile 0: features q*4..q*4+3, all valid (<20)
        int f0 = q * 4;
        v4f bi  = *(const v4f*)&cb2[f0];
        v4f tph = *(const v4f*)&tp[(w * 16 + c) * 20 + f0];
        v4f ts, pr;
#pragma unroll
        for (int r = 0; r < 4; ++r) {
            ts[r] = acc40[r] + bi[r];
            pr[r] = tph[r] + lam * ts[r];
        }
        *(v4f*)&outS[sample * 20 + f0] = ts;
        *(v4f*)&outP[sample * 20 + f0] = pr;
        *(v4f*)&outF[sample * 20 + f0] = tph;
    }
    if (q == 0) {  // ftile 1: features 16..19 valid only for q==0
        v4f bi  = *(const v4f*)&cb2[16];
        v4f tph = *(const v4f*)&tp[(w * 16 + c) * 20 + 16];
        v4f ts, pr;
#pragma unroll
        for (int r = 0; r < 4; ++r) {
            ts[r] = acc41[r] + bi[r];
            pr[r] = tph[r] + lam * ts[r];
        }
        *(v4f*)&outS[sample * 20 + 16] = ts;
        *(v4f*)&outP[sample * 20 + 16] = pr;
        *(v4f*)&outF[sample * 20 + 16] = tph;
    }
}

extern "C" void kernel_launch(void* const* d_in, const int* in_sizes, int n_in,
                              void* d_out, int out_size, void* d_ws, size_t ws_size,
                              hipStream_t stream)
{
    const float* history = (const float*)d_in[0];
    const float* enc_w1  = (const float*)d_in[1];
    const float* enc_b1  = (const float*)d_in[2];
    const float* enc_w2  = (const float*)d_in[3];
    const float* enc_b2  = (const float*)d_in[4];
    const float* cor_w1  = (const float*)d_in[5];
    const float* cor_b1  = (const float*)d_in[6];
    const float* cor_w2  = (const float*)d_in[7];
    const float* cor_b2  = (const float*)d_in[8];
    const float* alpha   = (const float*)d_in[9];
    const float* beta    = (const float*)d_in[10];
    const float* gamma   = (const float*)d_in[11];
    /* d_in[12] = tau, unused (TAU_INT compile-time) */
    const float* lmix    = (const float*)d_in[13];

    prep_kernel<<<105, 256, 0, stream>>>(enc_w1, enc_w2, cor_w1, cor_w2,
                                         alpha, beta, gamma, lmix,
                                         (unsigned char*)d_ws);
    fused_kernel<<<NROWS / 64, 256, 0, stream>>>(history, enc_b1, enc_b2, cor_b1, cor_b2,
                                                 (const unsigned char*)d_ws, (float*)d_out);
}

// Round 6
// 200.313 us; speedup vs baseline: 1.0982x; 1.0347x over previous
//
#include <hip/hip_runtime.h>
#include <hip/hip_bf16.h>

// Problem constants
#define NROWS 262144
#define HISTC 24
#define FOREC 20

// MFMA fragment vector types (gfx950 16x16x32 bf16: v8bf16 in, v4f32 acc)
typedef __bf16        v8bf __attribute__((ext_vector_type(8)));
typedef float         v4f  __attribute__((ext_vector_type(4)));
typedef float         v2f  __attribute__((ext_vector_type(2)));
typedef unsigned int  v4u  __attribute__((ext_vector_type(4)));
typedef unsigned int  v2u  __attribute__((ext_vector_type(2)));

// Workspace layout (bytes): [0..16) scalars a,b,g,lam ; then swizzled bf16 weights.
// Swizzle: block (ntile,ktile) of 64 lanes x 8 bf16, elem ((nt*KT+kt)*64 + lane)*8 + j
// holding W^T[feat = nt*16 + (lane&15)][k = kt*32 + (lane>>4)*8 + j]  (OOB -> 0).
// WT4 is REPLICATED to 16 nt-slots (real nt = slot&1) so the generic cross-layer
// prefetch index ((w*4+ft)*8+kt) is valid for layer 4 too.
#define WS_WT1_OFF 64
#define WT1_ELEMS 16384    /* 16 nt * 2 kt * 512 */
#define WT2_ELEMS 65536    /* 16 nt * 8 kt * 512 */
#define WT3_ELEMS 65536
#define WT4R_ELEMS 65536   /* 16 nt-slots (real nt = slot&1) * 8 kt * 512 */

// 2*log2(e): tanh(y) = 1 - 2/(exp2(y*2log2e)+1)
#define TANH_C 2.885390081777927f

__device__ __forceinline__ unsigned short f2bf(float x) {
    unsigned u = __builtin_bit_cast(unsigned, x);
    u += 0x7FFFu + ((u >> 16) & 1u);          // round-to-nearest-even
    return (unsigned short)(u >> 16);
}

// pack two fp32 -> bf16x2 with round-half-up: 2 adds + 1 v_perm (vs ~6 instr RNE).
// Differs from RNE only on exact-tie mantissas (1 ulp); well inside threshold.
__device__ __forceinline__ unsigned packbf2(float a, float b) {
    unsigned ua = __builtin_bit_cast(unsigned, a) + 0x8000u;
    unsigned ub = __builtin_bit_cast(unsigned, b) + 0x8000u;
    // dst = [ub.b3, ub.b2, ua.b3, ua.b2] = (ub_hi16 << 16) | ua_hi16
    return __builtin_amdgcn_perm(ub, ua, 0x07060302u);
}

// Barrier with LDS-visibility only: does NOT drain vmcnt, so in-flight global
// (weight-prefetch) loads survive the barrier. __syncthreads() would force the
// compiler to emit s_waitcnt vmcnt(0) and kill the cross-layer pipeline.
__device__ __forceinline__ void lds_barrier() {
    asm volatile("s_waitcnt lgkmcnt(0)\n\ts_barrier" ::: "memory");
}

// ---------------- prep: scalars + weight transpose/convert/swizzle ----------------
// 8 elems/thread, 16B stores. 212992 elems = 104 blocks; block 104 does scalars.
__global__ void prep_kernel(const float* __restrict__ w1, const float* __restrict__ w2,
                            const float* __restrict__ w3, const float* __restrict__ w4,
                            const float* __restrict__ alpha, const float* __restrict__ beta,
                            const float* __restrict__ gamma, const float* __restrict__ lmix,
                            unsigned char* __restrict__ ws)
{
    if (blockIdx.x == 104) {                    // scalar block
        int t = threadIdx.x;
        float* wsf = (float*)ws;
        if (t == 0) wsf[0] = 1.0f / (1.0f + expf(-alpha[0]));
        else if (t == 1) wsf[1] = 1.0f / (1.0f + expf(-beta[0]));
        else if (t == 2) wsf[2] = fabsf(gamma[0]);
        else if (t == 3) wsf[3] = 1.0f / (1.0f + expf(-lmix[0]));
        return;
    }
    int idx = (blockIdx.x * 256 + threadIdx.x) * 8;   // elem base, 8 per thread
    const float* src;
    int KT, Kreal, Nreal, srcN, local, ntmask;
    unsigned short* dst = (unsigned short*)(ws + WS_WT1_OFF);
    if (idx < WT1_ELEMS) {
        local = idx; src = w1; KT = 2; Kreal = 44; Nreal = 256; srcN = 256; ntmask = 255;
    } else if (idx < WT1_ELEMS + WT2_ELEMS) {
        local = idx - WT1_ELEMS; dst += WT1_ELEMS;
        src = w2; KT = 8; Kreal = 256; Nreal = 256; srcN = 256; ntmask = 255;
    } else if (idx < WT1_ELEMS + WT2_ELEMS + WT3_ELEMS) {
        local = idx - (WT1_ELEMS + WT2_ELEMS); dst += WT1_ELEMS + WT2_ELEMS;
        src = w3; KT = 8; Kreal = 256; Nreal = 256; srcN = 256; ntmask = 255;
    } else {
        local = idx - (WT1_ELEMS + WT2_ELEMS + WT3_ELEMS);
        dst += WT1_ELEMS + WT2_ELEMS + WT3_ELEMS;
        src = w4; KT = 8; Kreal = 256; Nreal = 20; srcN = 20; ntmask = 1;  // replicate
    }
    int L   = (local >> 3) & 63;
    int blk = local >> 9;
    int kt = blk % KT, nt = (blk / KT) & ntmask;
    int cc = L & 15,  qq = L >> 4;
    int feat = nt * 16 + cc;
    int kbase = kt * 32 + qq * 8;
    unsigned short tmp[8];
#pragma unroll
    for (int j = 0; j < 8; ++j) {
        int k = kbase + j;
        float v = (k < Kreal && feat < Nreal) ? src[k * srcN + feat] : 0.0f;
        tmp[j] = f2bf(v);
    }
    v4u pk;
    pk[0] = tmp[0] | ((unsigned)tmp[1] << 16);
    pk[1] = tmp[2] | ((unsigned)tmp[3] << 16);
    pk[2] = tmp[4] | ((unsigned)tmp[5] << 16);
    pk[3] = tmp[6] | ((unsigned)tmp[7] << 16);
    *(v4u*)&dst[local] = pk;
}

// ---------------- fused main kernel ----------------
// 4 waves, 64 samples/block. Wave w: 4 ftiles (features w*64..+63) x 4 stiles.
// Weight frags software-pipelined 2-deep through a 3-slot rotating buffer A[3][4];
// the last two kt iterations prefetch the NEXT layer's kt0/kt1. With lds_barrier()
// (lgkmcnt-only) those loads genuinely stay in flight across tanh + both barriers.
// S0 = rotation phase on entry (compile-time); exit phase = (S0+KT)%3.
template<int KT, int KTN, int S0>
__device__ __forceinline__ void layer_pipe(unsigned short* buf,
        const v4u* __restrict__ wp, const v4u* __restrict__ wpn,
        const float* __restrict__ bias, v4u A[3][4],
        int w, int c, int q, int lane)
{
    v4f acc[4][4];
#pragma unroll
    for (int ft = 0; ft < 4; ++ft)
#pragma unroll
        for (int st = 0; st < 4; ++st) {
            v4f z = {0.0f, 0.0f, 0.0f, 0.0f};
            acc[ft][st] = z;
        }

#pragma unroll
    for (int kt = 0; kt < KT; ++kt) {
        const int cs = (S0 + kt) % 3;
        const int ps = (S0 + kt + 2) % 3;
        if (kt + 2 < KT) {
#pragma unroll
            for (int ft = 0; ft < 4; ++ft)
                A[ps][ft] = wp[((w * 4 + ft) * KT + kt + 2) * 64 + lane];
        } else {
#pragma unroll
            for (int ft = 0; ft < 4; ++ft)
                A[ps][ft] = wpn[((w * 4 + ft) * KTN + (kt + 2 - KT)) * 64 + lane];
        }
#pragma unroll
        for (int st = 0; st < 4; ++st) {
            v4u braw = *(const v4u*)&buf[(st * 16 + c) * 264 + kt * 32 + q * 8];
            v8bf bb = __builtin_bit_cast(v8bf, braw);
#pragma unroll
            for (int ft = 0; ft < 4; ++ft)
                acc[ft][st] = __builtin_amdgcn_mfma_f32_16x16x32_bf16(
                    __builtin_bit_cast(v8bf, A[cs][ft]), bb, acc[ft][st], 0, 0, 0);
        }
    }

    lds_barrier();   // all reads done before in-place overwrite (vmcnt NOT drained)

    // Epilogue: lane (q,c) holds sample c, features base+q*4..+3 per tile.
    // tanh(acc+bi) = tanh-core(acc*C + bi*C): bias folded into the scale fma.
#pragma unroll
    for (int ft = 0; ft < 4; ++ft) {
        v4f bi = *(const v4f*)&bias[w * 64 + ft * 16 + q * 4];
        v4f bic;
#pragma unroll
        for (int r = 0; r < 4; ++r) bic[r] = bi[r] * TANH_C;
#pragma unroll
        for (int st = 0; st < 4; ++st) {
            float x[4];
#pragma unroll
            for (int r = 0; r < 4; ++r) {
                float t = __builtin_fmaf(acc[ft][st][r], TANH_C, bic[r]);
                float p = __builtin_amdgcn_exp2f(t);
                float rc = __builtin_amdgcn_rcpf(p + 1.0f);
                x[r] = __builtin_fmaf(-2.0f, rc, 1.0f);
            }
            v2u d; d[0] = packbf2(x[0], x[1]); d[1] = packbf2(x[2], x[3]);
            *(v2u*)&buf[(st * 16 + c) * 264 + w * 64 + ft * 16 + q * 4] = d;
        }
    }
    lds_barrier();
}

__global__ __launch_bounds__(256, 3) void fused_kernel(
    const float* __restrict__ history,
    const float* __restrict__ eb1, const float* __restrict__ eb2,
    const float* __restrict__ cb1, const float* __restrict__ cb2,
    const unsigned char* __restrict__ ws, float* __restrict__ out)
{
    __shared__ unsigned short buf[64 * 264];   // 33792 B, in-place act buffer
    __shared__ float tp[64 * 20];              // 5120 B fp32 T_physics

    const int tid  = threadIdx.x;
    const int w    = tid >> 6;                 // 4 waves
    const int lane = tid & 63;
    const int c    = lane & 15;
    const int q    = lane >> 4;
    const int row0 = blockIdx.x << 6;          // 64 samples per WG
    const float* wsf = (const float*)ws;
    const v4u* wp1 = (const v4u*)(ws + WS_WT1_OFF);
    const v4u* wp2 = wp1 + WT1_ELEMS / 8;
    const v4u* wp3 = wp2 + WT2_ELEMS / 8;
    const v4u* wp4 = wp3 + WT3_ELEMS / 8;

    // Preload layer-1 weight frags (kt0 -> slot0, kt1 -> slot1) BEFORE staging,
    // so the L2 round-trip overlaps the history load + physics.
    v4u A[3][4];
#pragma unroll
    for (int ft = 0; ft < 4; ++ft) {
        A[0][ft] = wp1[((w * 4 + ft) * 2 + 0) * 64 + lane];
        A[1][ft] = wp1[((w * 4 + ft) * 2 + 1) * 64 + lane];
    }

    // --- staging: global float4 -> bf16x4 pack in regs -> one ds_write_b64 ---
#pragma unroll
    for (int i = 0; i < 2; ++i) {
        int e = tid + i * 256;
        if (e < 384) {
            int r  = e / 6, c4 = e - r * 6;
            v4f h4 = *(const v4f*)&history[(long)(row0 + r) * 24 + c4 * 4];
            v2u d; d[0] = packbf2(h4[0], h4[1]); d[1] = packbf2(h4[2], h4[3]);
            *(v2u*)&buf[r * 264 + c4 * 4] = d;
        }
    }
    // zero-fill cols 44..63 (pad vs stale LDS): 64 rows x 5 b64-groups = 320 tasks
#pragma unroll
    for (int i = 0; i < 2; ++i) {
        int e = tid + i * 256;
        if (e < 320) {
            int r = e / 5, g = e - r * 5;
            v2u z = {0u, 0u};
            *(v2u*)&buf[r * 264 + 44 + g * 4] = z;
        }
    }
    // physics: one thread per row; last-6 history read direct from global (L2-hot)
    if (tid < 64) {
        const float* hrow = &history[(long)(row0 + tid) * 24];
        v2f h18 = *(const v2f*)&hrow[18];
        v4f h20 = *(const v4f*)&hrow[20];
        float pa = wsf[0], pb = wsf[1], pg = wsf[2];
        float d0 = h18[0], d1 = h18[1], d2 = h20[0];
        float d3 = h20[1], d4 = h20[2], d5 = h20[3];
        float T = d5;
#pragma unroll
        for (int s = 0; s < 20; ++s) {
            float t3 = T * T * T;
            float Tn = T - pa * T;
            Tn = Tn - pb * d0;
            Tn = Tn - pg * t3;
            tp[tid * 20 + s] = Tn;
            buf[tid * 264 + 24 + s] = f2bf(Tn);
            d0 = d1; d1 = d2; d2 = d3; d3 = d4; d4 = d5; d5 = Tn;
            T = Tn;
        }
    }
    lds_barrier();

    // Rotation phases: L1 S0=0 (KT=2) -> L2 S0=2 (KT=8) -> L3 S0=1 -> L4 S0=0.
    layer_pipe<2, 8, 0>(buf, wp1, wp2, eb1, A, w, c, q, lane);   // 44(pad64)->256
    layer_pipe<8, 8, 2>(buf, wp2, wp3, eb2, A, w, c, q, lane);   // 256->256
    layer_pipe<8, 8, 1>(buf, wp3, wp4, cb1, A, w, c, q, lane);   // 256->256

    // Layer 4: 256 -> 20. Wave w = stile w; A[0][0..1]/A[1][0..1] hold kt0/kt1
    // (replicated wt4: slot w*4+ft, real nt = ft for ft<2).
    v4f acc40 = {0.0f, 0.0f, 0.0f, 0.0f}, acc41 = {0.0f, 0.0f, 0.0f, 0.0f};
#pragma unroll
    for (int kt = 0; kt < 8; ++kt) {
        const int cs = kt % 3, ps = (kt + 2) % 3;
        if (kt + 2 < 8) {
            A[ps][0] = wp4[((w * 4 + 0) * 8 + kt + 2) * 64 + lane];
            A[ps][1] = wp4[((w * 4 + 1) * 8 + kt + 2) * 64 + lane];
        }
        v4u braw = *(const v4u*)&buf[(w * 16 + c) * 264 + kt * 32 + q * 8];
        v8bf bb = __builtin_bit_cast(v8bf, braw);
        acc40 = __builtin_amdgcn_mfma_f32_16x16x32_bf16(
            __builtin_bit_cast(v8bf, A[cs][0]), bb, acc40, 0, 0, 0);
        acc41 = __builtin_amdgcn_mfma_f32_16x16x32_bf16(
            __builtin_bit_cast(v8bf, A[cs][1]), bb, acc41, 0, 0, 0);
    }

    const float lam = wsf[3];
    const long sample = (long)row0 + w * 16 + c;
    float* outP = out;                         // T_pred
    float* outF = out + (long)NROWS * 20;      // T_physics
    float* outS = out + (long)NROWS * 40;      // T_soft
    {   // ftile 0: features q*4..q*4+3, all valid (<20)
        int f0 = q * 4;
        v4f bi  = *(const v4f*)&cb2[f0];
        v4f tph = *(const v4f*)&tp[(w * 16 + c) * 20 + f0];
        v4f ts, pr;
#pragma unroll
        for (int r = 0; r < 4; ++r) {
            ts[r] = acc40[r] + bi[r];
            pr[r] = tph[r] + lam * ts[r];
        }
        *(v4f*)&outS[sample * 20 + f0] = ts;
        *(v4f*)&outP[sample * 20 + f0] = pr;
        *(v4f*)&outF[sample * 20 + f0] = tph;
    }
    if (q == 0) {  // ftile 1: features 16..19 valid only for q==0
        v4f bi  = *(const v4f*)&cb2[16];
        v4f tph = *(const v4f*)&tp[(w * 16 + c) * 20 + 16];
        v4f ts, pr;
#pragma unroll
        for (int r = 0; r < 4; ++r) {
            ts[r] = acc41[r] + bi[r];
            pr[r] = tph[r] + lam * ts[r];
        }
        *(v4f*)&outS[sample * 20 + 16] = ts;
        *(v4f*)&outP[sample * 20 + 16] = pr;
        *(v4f*)&outF[sample * 20 + 16] = tph;
    }
}

extern "C" void kernel_launch(void* const* d_in, const int* in_sizes, int n_in,
                              void* d_out, int out_size, void* d_ws, size_t ws_size,
                              hipStream_t stream)
{
    const float* history = (const float*)d_in[0];
    const float* enc_w1  = (const float*)d_in[1];
    const float* enc_b1  = (const float*)d_in[2];
    const float* enc_w2  = (const float*)d_in[3];
    const float* enc_b2  = (const float*)d_in[4];
    const float* cor_w1  = (const float*)d_in[5];
    const float* cor_b1  = (const float*)d_in[6];
    const float* cor_w2  = (const float*)d_in[7];
    const float* cor_b2  = (const float*)d_in[8];
    const float* alpha   = (const float*)d_in[9];
    const float* beta    = (const float*)d_in[10];
    const float* gamma   = (const float*)d_in[11];
    /* d_in[12] = tau, unused (TAU_INT compile-time) */
    const float* lmix    = (const float*)d_in[13];

    prep_kernel<<<105, 256, 0, stream>>>(enc_w1, enc_w2, cor_w1, cor_w2,
                                         alpha, beta, gamma, lmix,
                                         (unsigned char*)d_ws);
    fused_kernel<<<NROWS / 64, 256, 0, stream>>>(history, enc_b1, enc_b2, cor_b1, cor_b2,
                                                 (const unsigned char*)d_ws, (float*)d_out);
}